// Round 1
// baseline (200.189 us; speedup 1.0000x reference)
//
#include <hip/hip_runtime.h>

#define NEGF 1.0e12f

constexpr int Hdim = 768;
constexpr int NC   = 160;   // 128 (W1) + 32 (W2) output columns
constexpr int ROWS = 4096;  // B*S
constexpr int SEQ  = 512;

// ---------------------------------------------------------------------------
// Kernel A: t-partial = x @ [W1 | W2], K split in 2 chunks of 384.
// Grid (128, 2) x 256 threads. Block tile: 32 rows x 160 cols.
// Per-thread: 4 rows x 5 cols register tile.
// ---------------------------------------------------------------------------
__global__ __launch_bounds__(256) void gemm_partial_k(
    const float* __restrict__ x, const float* __restrict__ W1,
    const float* __restrict__ W2, float* __restrict__ partial)
{
    __shared__ float xs[32][33];   // +1 pad; reads are row-broadcast anyway
    __shared__ float ws[32][NC];   // stride 160 % 32 == 0; col stride 5 is bank-clean

    const int tid = threadIdx.x;
    const int r0  = blockIdx.x * 32;
    const int kc  = blockIdx.y;          // 0 or 1
    const int k0  = kc * 384;
    const int cg  = tid & 31;            // cols 5*cg .. 5*cg+4
    const int rg  = tid >> 5;            // rows 4*rg .. 4*rg+3

    float acc[4][5];
#pragma unroll
    for (int i = 0; i < 4; i++)
#pragma unroll
        for (int j = 0; j < 5; j++) acc[i][j] = 0.0f;

    for (int kt = 0; kt < 384; kt += 32) {
        const int kbase = k0 + kt;
        // stage x tile: 32 rows x 32 k, one float4 per thread
        {
            const int row = tid >> 3;
            const int k4  = (tid & 7) << 2;
            float4 v = *(const float4*)(x + (size_t)(r0 + row) * Hdim + kbase + k4);
            xs[row][k4 + 0] = v.x; xs[row][k4 + 1] = v.y;
            xs[row][k4 + 2] = v.z; xs[row][k4 + 3] = v.w;
        }
        // stage W tile: 32 k x 160 cols = 5120 floats, 20 per thread, coalesced
#pragma unroll
        for (int rep = 0; rep < 20; rep++) {
            int idx = rep * 256 + tid;
            int k   = idx / NC;
            int c   = idx - k * NC;
            float w = (c < 128) ? W1[(size_t)(kbase + k) * 128 + c]
                                : W2[(size_t)(kbase + k) * 32 + (c - 128)];
            ws[k][c] = w;
        }
        __syncthreads();

        for (int kk = 0; kk < 32; kk++) {
            float xv[4], wv[5];
#pragma unroll
            for (int i = 0; i < 4; i++) xv[i] = xs[rg * 4 + i][kk];
#pragma unroll
            for (int j = 0; j < 5; j++) wv[j] = ws[kk][cg * 5 + j];
#pragma unroll
            for (int i = 0; i < 4; i++)
#pragma unroll
                for (int j = 0; j < 5; j++) acc[i][j] += xv[i] * wv[j];
        }
        __syncthreads();
    }

    float* dst = partial + (size_t)kc * ROWS * NC;
#pragma unroll
    for (int i = 0; i < 4; i++) {
        size_t roff = (size_t)(r0 + rg * 4 + i) * NC + cg * 5;
#pragma unroll
        for (int j = 0; j < 5; j++) dst[roff + j] = acc[i][j];
    }
}

// ---------------------------------------------------------------------------
// Kernel B: combine K-partials + bias, apply RoPE, split typing channels.
// 4 rows per 256-thread block; 64 threads per row (32 rope units + 32 typing).
// Thread i (i<32) owns t[4i..4i+3]: start pair (t[4i],t[4i+2]),
// end pair (t[4i+1],t[4i+3]) — rope entirely thread-local.
// ---------------------------------------------------------------------------
__global__ __launch_bounds__(256) void combine_rope_k(
    const float* __restrict__ partial, const float* __restrict__ b1,
    const float* __restrict__ b2, float* __restrict__ startW,
    float* __restrict__ endW, float* __restrict__ tyn,
    float* __restrict__ tym)
{
    const int tid = threadIdx.x;
    const int row = blockIdx.x * 4 + (tid >> 6);
    const int u   = tid & 63;
    const int b   = row >> 9;
    const int s   = row & 511;
    const float* p0 = partial + (size_t)row * NC;
    const float* p1 = partial + (size_t)ROWS * NC + (size_t)row * NC;

    if (u < 32) {
        const int i = u;
        float4 a0 = *(const float4*)(p0 + 4 * i);
        float4 a1 = *(const float4*)(p1 + 4 * i);
        float t0 = a0.x + a1.x + b1[4 * i + 0];
        float t1 = a0.y + a1.y + b1[4 * i + 1];
        float t2 = a0.z + a1.z + b1[4 * i + 2];
        float t3 = a0.w + a1.w + b1[4 * i + 3];
        // freq_i = 10000^(-i/32)
        float freq = powf(10000.0f, -(float)i * (1.0f / 32.0f));
        float ang  = (float)s * freq;
        float sn = sinf(ang), cs = cosf(ang);
        // start pair = (t[4i], t[4i+2]); end pair = (t[4i+1], t[4i+3])
        float so0 = t0 * cs - t2 * sn;
        float so1 = t2 * cs + t0 * sn;
        float eo0 = t1 * cs - t3 * sn;
        float eo1 = t3 * cs + t1 * sn;
        *(float2*)(startW + (size_t)row * 64 + 2 * i) = make_float2(so0, so1);
        *(float2*)(endW   + (size_t)row * 64 + 2 * i) = make_float2(eo0, eo1);
    } else {
        const int j = u - 32;            // typing channel 0..31
        float t = p0[128 + j] + p1[128 + j] + b2[j];
        float v = t * 0.5f;
        const int l = j >> 1;
        // even channels broadcast along n; odd along m
        if ((j & 1) == 0) tyn[((size_t)b * 16 + l) * SEQ + s] = v;
        else              tym[((size_t)b * 16 + l) * SEQ + s] = v;
    }
}

// ---------------------------------------------------------------------------
// Kernel C: span dot + 16-plane broadcast epilogue with mask + tril.
// Grid (8 n-tiles, 8 m-tiles, 8 batches) x 256 threads; 64x64 (m,n) tile.
// ---------------------------------------------------------------------------
__global__ __launch_bounds__(256) void entity_k(
    const float* __restrict__ startW, const float* __restrict__ endW,
    const float* __restrict__ tyn, const float* __restrict__ tym,
    const int* __restrict__ amask, float* __restrict__ out)
{
    __shared__ float sA[64][65];   // start rows (m) — pad 65: bank-clean
    __shared__ float sB[64][65];   // end rows (n)
    __shared__ float tyn_s[16][64];
    __shared__ float tym_s[16][64];
    __shared__ float sp[64 * 64];  // span scores
    __shared__ float mrow[64];
    __shared__ float mcol[64];

    const int tid = threadIdx.x;
    const int b   = blockIdx.z;
    const int m0  = blockIdx.y * 64;
    const int n0  = blockIdx.x * 64;

    // stage start/end tiles (64 rows x 64 dims), float4 loads
    for (int t = tid; t < 64 * 16; t += 256) {
        int m  = t >> 4;
        int k4 = (t & 15) << 2;
        float4 v = *(const float4*)(startW + (size_t)(b * SEQ + m0 + m) * 64 + k4);
        sA[m][k4] = v.x; sA[m][k4 + 1] = v.y; sA[m][k4 + 2] = v.z; sA[m][k4 + 3] = v.w;
        float4 w = *(const float4*)(endW + (size_t)(b * SEQ + n0 + m) * 64 + k4);
        sB[m][k4] = w.x; sB[m][k4 + 1] = w.y; sB[m][k4 + 2] = w.z; sB[m][k4 + 3] = w.w;
    }
    for (int t = tid; t < 16 * 64; t += 256) {
        int l = t >> 6, i = t & 63;
        tym_s[l][i] = tym[((size_t)b * 16 + l) * SEQ + m0 + i];
        tyn_s[l][i] = tyn[((size_t)b * 16 + l) * SEQ + n0 + i];
    }
    if (tid < 64)       mrow[tid] = (float)amask[b * SEQ + m0 + tid];
    else if (tid < 128) mcol[tid - 64] = (float)amask[b * SEQ + n0 + (tid - 64)];
    __syncthreads();

    // span dots: thread = 4m x 4n register tile
    {
        const int ng = tid & 15, mg = tid >> 4;
        float acc[4][4];
#pragma unroll
        for (int i = 0; i < 4; i++)
#pragma unroll
            for (int j = 0; j < 4; j++) acc[i][j] = 0.0f;

        for (int k = 0; k < 64; k++) {
            float a[4], bv[4];
#pragma unroll
            for (int i = 0; i < 4; i++) a[i] = sA[mg * 4 + i][k];
#pragma unroll
            for (int j = 0; j < 4; j++) bv[j] = sB[ng * 4 + j][k];
#pragma unroll
            for (int i = 0; i < 4; i++)
#pragma unroll
                for (int j = 0; j < 4; j++) acc[i][j] += a[i] * bv[j];
        }
#pragma unroll
        for (int i = 0; i < 4; i++)
#pragma unroll
            for (int j = 0; j < 4; j++)
                sp[(mg * 4 + i) * 64 + ng * 4 + j] = acc[i][j] * 0.125f; // /sqrt(64)
    }
    __syncthreads();

    // write 16 L-planes; thread owns 4 consecutive n, loops 4 m-passes x 16 l
    {
        const int nq = tid & 15, mo = tid >> 4;
        float mc[4], cadd[4];
#pragma unroll
        for (int q = 0; q < 4; q++) {
            mc[q]   = mcol[nq * 4 + q];
            cadd[q] = -NEGF * (1.0f - mc[q]);
        }
        for (int l = 0; l < 16; l++) {
            float4 tn = *(const float4*)&tyn_s[l][nq * 4];
            const size_t obase = (size_t)(b * 16 + l) * SEQ;
#pragma unroll
            for (int pass = 0; pass < 4; pass++) {
                int m  = pass * 16 + mo;
                int gm = m0 + m;
                float tm   = tym_s[l][m];
                float mr   = mrow[m];
                float radd = -NEGF * (1.0f - mr);
                float4 spv = *(const float4*)&sp[m * 64 + nq * 4];
                float v0 = spv.x + tn.x + tm;
                float v1 = spv.y + tn.y + tm;
                float v2 = spv.z + tn.z + tm;
                float v3 = spv.w + tn.w + tm;
                v0 = v0 * mr + radd; v1 = v1 * mr + radd;
                v2 = v2 * mr + radd; v3 = v3 * mr + radd;
                v0 = v0 * mc[0] + cadd[0]; v1 = v1 * mc[1] + cadd[1];
                v2 = v2 * mc[2] + cadd[2]; v3 = v3 * mc[3] + cadd[3];
                int gn = n0 + nq * 4;
                if (gm > gn)     v0 -= NEGF;
                if (gm > gn + 1) v1 -= NEGF;
                if (gm > gn + 2) v2 -= NEGF;
                if (gm > gn + 3) v3 -= NEGF;
                *(float4*)(out + (obase + gm) * SEQ + gn) = make_float4(v0, v1, v2, v3);
            }
        }
    }
}

// ---------------------------------------------------------------------------
extern "C" void kernel_launch(void* const* d_in, const int* in_sizes, int n_in,
                              void* d_out, int out_size, void* d_ws, size_t ws_size,
                              hipStream_t stream) {
    const float* x     = (const float*)d_in[0];
    const float* W1    = (const float*)d_in[1];
    const float* b1    = (const float*)d_in[2];
    const float* W2    = (const float*)d_in[3];
    const float* b2    = (const float*)d_in[4];
    const int*   amask = (const int*)d_in[5];
    float* out = (float*)d_out;

    float* ws      = (float*)d_ws;
    float* partial = ws;                      // 2*4096*160 = 1,310,720 floats
    float* startW  = partial + 2 * ROWS * NC; // 4096*64
    float* endW    = startW + ROWS * 64;      // 4096*64
    float* tyn     = endW + ROWS * 64;        // 8*16*512
    float* tym     = tyn + 8 * 16 * SEQ;      // 8*16*512
    // total ~7.9 MB of d_ws

    hipLaunchKernelGGL(gemm_partial_k, dim3(128, 2), dim3(256), 0, stream,
                       x, W1, W2, partial);
    hipLaunchKernelGGL(combine_rope_k, dim3(ROWS / 4), dim3(256), 0, stream,
                       partial, b1, b2, startW, endW, tyn, tym);
    hipLaunchKernelGGL(entity_k, dim3(8, 8, 8), dim3(256), 0, stream,
                       startW, endW, tyn, tym, amask, out);
}

// Round 2
// 168.221 us; speedup vs baseline: 1.1900x; 1.1900x over previous
//
#include <hip/hip_runtime.h>

#define NEGF 1.0e12f

constexpr int Hdim = 768;
constexpr int NC   = 160;   // 128 (W1) + 32 (W2) output columns
constexpr int ROWS = 4096;  // B*S
constexpr int SEQ  = 512;
constexpr int KSPLIT = 4;   // K chunks of 192

typedef __attribute__((ext_vector_type(8))) short  short8;   // 8 bf16
typedef __attribute__((ext_vector_type(4))) float  floatx4;

__device__ inline unsigned short f2bf(float f) {
    union { float f; unsigned u; } v; v.f = f;
    return (unsigned short)((v.u + 0x8000u) >> 16);   // round-half-up, fine at this tol
}

// ---------------------------------------------------------------------------
// Kernel A: partial[kc] = x @ [W1|W2] over K-chunk kc, bf16 MFMA 16x16x32.
// Grid (64 row-blocks, 4 k-chunks) x 256 threads (4 waves).
// Block: 64 rows x 160 cols; wave w owns rows w*16..w*16+15, all 160 cols.
// LDS: xs[64][40] halves (A: m-major, k-contig), ws[160][40] (B^T: n-major).
// Row stride 40 halves = 80B: 16B-aligned rows, bank-even for b128.
// ---------------------------------------------------------------------------
__global__ __launch_bounds__(256) void gemm_mfma_k(
    const float* __restrict__ x, const float* __restrict__ W1,
    const float* __restrict__ W2, float* __restrict__ partial)
{
    __shared__ __align__(16) unsigned short xs[64 * 40];
    __shared__ __align__(16) unsigned short ws[NC * 40];

    const int tid  = threadIdx.x;
    const int wave = tid >> 6;
    const int lane = tid & 63;
    const int quad = lane >> 4;
    const int nl   = lane & 15;
    const int r0   = blockIdx.x * 64;
    const int k0   = blockIdx.y * 192;

    floatx4 acc[10];
#pragma unroll
    for (int t = 0; t < 10; t++) acc[t] = (floatx4)(0.0f);

    for (int kt = 0; kt < 192; kt += 32) {
        const int kb = k0 + kt;
        // stage x: 64 rows x 32 k -> bf16. thread: row=tid>>2, kq=(tid&3)*8
        {
            const int row = tid >> 2;
            const int kq  = (tid & 3) * 8;
            const float* xp = x + (size_t)(r0 + row) * Hdim + kb + kq;
            float4 v0 = *(const float4*)xp;
            float4 v1 = *(const float4*)(xp + 4);
            short8 sv;
            sv[0] = (short)f2bf(v0.x); sv[1] = (short)f2bf(v0.y);
            sv[2] = (short)f2bf(v0.z); sv[3] = (short)f2bf(v0.w);
            sv[4] = (short)f2bf(v1.x); sv[5] = (short)f2bf(v1.y);
            sv[6] = (short)f2bf(v1.z); sv[7] = (short)f2bf(v1.w);
            *(short8*)(xs + row * 40 + kq) = sv;
        }
        // stage W transposed -> ws[c][k]: 3 groups of 64 cols (last half-masked)
#pragma unroll
        for (int g = 0; g < 3; g++) {
            const int c   = g * 64 + (tid & 63);
            const int kq2 = (tid >> 6) * 8;
            if (c < NC) {
                float f[8];
                if (c < 128) {
                    const float* wp = W1 + (size_t)(kb + kq2) * 128 + c;
#pragma unroll
                    for (int j = 0; j < 8; j++) f[j] = wp[j * 128];
                } else {
                    const float* wp = W2 + (size_t)(kb + kq2) * 32 + (c - 128);
#pragma unroll
                    for (int j = 0; j < 8; j++) f[j] = wp[j * 32];
                }
                short8 sv;
#pragma unroll
                for (int j = 0; j < 8; j++) sv[j] = (short)f2bf(f[j]);
                *(short8*)(ws + c * 40 + kq2) = sv;
            }
        }
        __syncthreads();

        short8 af = *(const short8*)(xs + (wave * 16 + nl) * 40 + quad * 8);
#pragma unroll
        for (int t = 0; t < 10; t++) {
            short8 bf = *(const short8*)(ws + (t * 16 + nl) * 40 + quad * 8);
            acc[t] = __builtin_amdgcn_mfma_f32_16x16x32_bf16(af, bf, acc[t], 0, 0, 0);
        }
        __syncthreads();
    }

    // D layout: row = quad*4 + reg, col = nl
    float* pout = partial + (size_t)blockIdx.y * ROWS * NC;
#pragma unroll
    for (int t = 0; t < 10; t++) {
#pragma unroll
        for (int r = 0; r < 4; r++) {
            pout[(size_t)(r0 + wave * 16 + quad * 4 + r) * NC + t * 16 + nl] = acc[t][r];
        }
    }
}

// ---------------------------------------------------------------------------
// Kernel B: combine 4 K-partials + bias, RoPE, emit bf16 start/end
// (start pre-scaled by 1/8) + fp32 typing planes.
// 4 rows per 256-thread block; 64 threads/row (32 rope units + 32 typing).
// ---------------------------------------------------------------------------
__global__ __launch_bounds__(256) void combine_rope_k(
    const float* __restrict__ partial, const float* __restrict__ b1,
    const float* __restrict__ b2, unsigned short* __restrict__ startbf,
    unsigned short* __restrict__ endbf, float* __restrict__ tyn,
    float* __restrict__ tym)
{
    const int tid = threadIdx.x;
    const int row = blockIdx.x * 4 + (tid >> 6);
    const int u   = tid & 63;
    const int b   = row >> 9;
    const int s   = row & 511;
    const float* p0 = partial + (size_t)row * NC;
    const size_t cstride = (size_t)ROWS * NC;

    if (u < 32) {
        const int i = u;
        float4 a0 = *(const float4*)(p0 + 4 * i);
        float4 a1 = *(const float4*)(p0 + cstride + 4 * i);
        float4 a2 = *(const float4*)(p0 + 2 * cstride + 4 * i);
        float4 a3 = *(const float4*)(p0 + 3 * cstride + 4 * i);
        float t0 = a0.x + a1.x + a2.x + a3.x + b1[4 * i + 0];
        float t1 = a0.y + a1.y + a2.y + a3.y + b1[4 * i + 1];
        float t2 = a0.z + a1.z + a2.z + a3.z + b1[4 * i + 2];
        float t3 = a0.w + a1.w + a2.w + a3.w + b1[4 * i + 3];
        float freq = __powf(10000.0f, -(float)i * (1.0f / 32.0f));
        float ang  = (float)s * freq;
        float sn, cs;
        __sincosf(ang, &sn, &cs);
        // start pair = (t[4i], t[4i+2]); end pair = (t[4i+1], t[4i+3])
        float so0 = (t0 * cs - t2 * sn) * 0.125f;   // fold 1/sqrt(64)
        float so1 = (t2 * cs + t0 * sn) * 0.125f;
        float eo0 = t1 * cs - t3 * sn;
        float eo1 = t3 * cs + t1 * sn;
        ushort2 sp; sp.x = f2bf(so0); sp.y = f2bf(so1);
        ushort2 ep; ep.x = f2bf(eo0); ep.y = f2bf(eo1);
        *(ushort2*)(startbf + (size_t)row * 64 + 2 * i) = sp;
        *(ushort2*)(endbf   + (size_t)row * 64 + 2 * i) = ep;
    } else {
        const int j = u - 32;
        float t = p0[128 + j] + p0[cstride + 128 + j] + p0[2 * cstride + 128 + j]
                + p0[3 * cstride + 128 + j] + b2[j];
        float v = t * 0.5f;
        const int l = j >> 1;
        if ((j & 1) == 0) tyn[((size_t)b * 16 + l) * SEQ + s] = v;
        else              tym[((size_t)b * 16 + l) * SEQ + s] = v;
    }
}

// ---------------------------------------------------------------------------
// Kernel C: span = start.end^T via bf16 MFMA + 16-plane epilogue from D regs.
// Grid (8 n-tiles, 8 m-tiles, 8 batches) x 256 threads; 64x64 (m,n) tile.
// Wave w owns m-strip w*16..w*16+15 x all 64 n. acc: 4 n-tiles x float4.
// ---------------------------------------------------------------------------
__global__ __launch_bounds__(256) void entity_k(
    const unsigned short* __restrict__ startbf, const unsigned short* __restrict__ endbf,
    const float* __restrict__ tyn, const float* __restrict__ tym,
    const int* __restrict__ amask, float* __restrict__ out)
{
    __shared__ __align__(16) unsigned short sA[64 * 72];  // [m][k] bf16, stride 72 halves
    __shared__ __align__(16) unsigned short sB[64 * 72];  // [n][k] bf16
    __shared__ float tyn_s[16 * 64];
    __shared__ float tym_s[16 * 64];
    __shared__ float mrow_s[64];
    __shared__ float mcol_s[64];

    const int tid = threadIdx.x;
    const int b   = blockIdx.z;
    const int m0  = blockIdx.y * 64;
    const int n0  = blockIdx.x * 64;

    for (int t = tid; t < 512; t += 256) {
        int row = t >> 3;
        int kq  = (t & 7) * 8;
        *(short8*)(sA + row * 72 + kq) =
            *(const short8*)(startbf + (size_t)(b * SEQ + m0 + row) * 64 + kq);
        *(short8*)(sB + row * 72 + kq) =
            *(const short8*)(endbf + (size_t)(b * SEQ + n0 + row) * 64 + kq);
    }
    for (int t = tid; t < 16 * 64; t += 256) {
        int l = t >> 6, i = t & 63;
        tym_s[t] = tym[((size_t)b * 16 + l) * SEQ + m0 + i];
        tyn_s[t] = tyn[((size_t)b * 16 + l) * SEQ + n0 + i];
    }
    if (tid < 64)       mrow_s[tid] = (float)amask[b * SEQ + m0 + tid];
    else if (tid < 128) mcol_s[tid - 64] = (float)amask[b * SEQ + n0 + (tid - 64)];
    __syncthreads();

    const int wave = tid >> 6;
    const int lane = tid & 63;
    const int quad = lane >> 4;
    const int nl   = lane & 15;

    short8 a0 = *(const short8*)(sA + (wave * 16 + nl) * 72 + quad * 8);
    short8 a1 = *(const short8*)(sA + (wave * 16 + nl) * 72 + 32 + quad * 8);

    floatx4 acc[4];
#pragma unroll
    for (int t = 0; t < 4; t++) acc[t] = (floatx4)(0.0f);
#pragma unroll
    for (int t = 0; t < 4; t++) {
        short8 bf0 = *(const short8*)(sB + (t * 16 + nl) * 72 + quad * 8);
        short8 bf1 = *(const short8*)(sB + (t * 16 + nl) * 72 + 32 + quad * 8);
        acc[t] = __builtin_amdgcn_mfma_f32_16x16x32_bf16(a0, bf0, acc[t], 0, 0, 0);
        acc[t] = __builtin_amdgcn_mfma_f32_16x16x32_bf16(a1, bf1, acc[t], 0, 0, 0);
    }

    // epilogue straight from D regs: elem (t, r) sits at row quad*4+r, col t*16+nl
    float mr[4], radd[4];
#pragma unroll
    for (int r = 0; r < 4; r++) {
        mr[r]   = mrow_s[wave * 16 + quad * 4 + r];
        radd[r] = -NEGF * (1.0f - mr[r]);
    }
    float mc[4], cadd[4];
#pragma unroll
    for (int t = 0; t < 4; t++) {
        mc[t]   = mcol_s[t * 16 + nl];
        cadd[t] = -NEGF * (1.0f - mc[t]);
    }
    const bool lower = (m0 > n0);
    const bool diag  = (m0 == n0);
    const int  lm    = wave * 16 + quad * 4;   // local row of reg r=0

    for (int l = 0; l < 16; l++) {
        float tmv[4];
#pragma unroll
        for (int r = 0; r < 4; r++) tmv[r] = tym_s[l * 64 + lm + r];
        float* ob = out + ((size_t)(b * 16 + l) * SEQ + m0 + lm) * SEQ + n0;
#pragma unroll
        for (int t = 0; t < 4; t++) {
            float tnv = tyn_s[l * 64 + t * 16 + nl];
#pragma unroll
            for (int r = 0; r < 4; r++) {
                float v = acc[t][r] + tnv + tmv[r];
                v = v * mr[r] + radd[r];
                v = v * mc[t] + cadd[t];
                if (lower) v -= NEGF;
                else if (diag && (lm + r > t * 16 + nl)) v -= NEGF;
                ob[(size_t)r * SEQ + t * 16 + nl] = v;
            }
        }
    }
}

// ---------------------------------------------------------------------------
extern "C" void kernel_launch(void* const* d_in, const int* in_sizes, int n_in,
                              void* d_out, int out_size, void* d_ws, size_t ws_size,
                              hipStream_t stream) {
    const float* x     = (const float*)d_in[0];
    const float* W1    = (const float*)d_in[1];
    const float* b1    = (const float*)d_in[2];
    const float* W2    = (const float*)d_in[3];
    const float* b2    = (const float*)d_in[4];
    const int*   amask = (const int*)d_in[5];
    float* out = (float*)d_out;

    char* base = (char*)d_ws;
    float*          partial = (float*)base;                                 // 4*4096*160*4 B
    unsigned short* startbf = (unsigned short*)(base + 10485760);           // 4096*64*2 B
    unsigned short* endbf   = (unsigned short*)(base + 10485760 + 524288);
    float*          tyn     = (float*)(base + 10485760 + 2 * 524288);       // 8*16*512*4 B
    float*          tym     = (float*)(base + 10485760 + 2 * 524288 + 262144);

    hipLaunchKernelGGL(gemm_mfma_k, dim3(64, KSPLIT), dim3(256), 0, stream,
                       x, W1, W2, partial);
    hipLaunchKernelGGL(combine_rope_k, dim3(ROWS / 4), dim3(256), 0, stream,
                       partial, b1, b2, startbf, endbf, tyn, tym);
    hipLaunchKernelGGL(entity_k, dim3(8, 8, 8), dim3(256), 0, stream,
                       startbf, endbf, tyn, tym, amask, out);
}